// Round 1
// baseline (197.138 us; speedup 1.0000x reference)
//
#include <hip/hip_runtime.h>
#include <hip/hip_bf16.h>

// QNet: out[i] = w2 . relu( concat(embed[i], graph_embed[rep[i]]) @ w1^T + b1 ) + b2
// Split: h_pre = embed @ W1a^T  (bf16 MFMA, K=64)  +  Gb[rep[i]]  (precomputed fp32)
// where Gb[b][n] = b1[n] + sum_k graph_embed[b][k] * w1[n][64+k]

#define D_LAT 64
#define H_HID 128

typedef short bf16x8 __attribute__((ext_vector_type(8)));
typedef float f32x4  __attribute__((ext_vector_type(4)));

static __device__ inline short f2s(float f) {
    __bf16 h = (__bf16)f;               // compiler emits v_cvt_pk_bf16_f32 pairs
    return __builtin_bit_cast(short, h);
}

static __device__ inline bf16x8 cvt8(const float* __restrict__ p) {
    float4 a = *reinterpret_cast<const float4*>(p);
    float4 b = *reinterpret_cast<const float4*>(p + 4);
    bf16x8 r;
    r[0] = f2s(a.x); r[1] = f2s(a.y); r[2] = f2s(a.z); r[3] = f2s(a.w);
    r[4] = f2s(b.x); r[5] = f2s(b.y); r[6] = f2s(b.z); r[7] = f2s(b.w);
    return r;
}

// Gb[b][n] = b1[n] + sum_{k<64} graph_embed[b][k] * w1[n][64+k]
__global__ void gb_kernel(const float* __restrict__ ge, const float* __restrict__ w1,
                          const float* __restrict__ b1, float* __restrict__ gb) {
    __shared__ float s[D_LAT];
    const int b = blockIdx.x, n = threadIdx.x;
    if (threadIdx.x < D_LAT) s[threadIdx.x] = ge[b * D_LAT + threadIdx.x];
    __syncthreads();
    float acc = b1[n];
    const float* wr = w1 + n * (2 * D_LAT) + D_LAT;
    #pragma unroll
    for (int k = 0; k < D_LAT; ++k) acc += s[k] * wr[k];
    gb[b * H_HID + n] = acc;
}

__global__ __launch_bounds__(256) void qnet_main(
        const float* __restrict__ embed, const int* __restrict__ rep,
        const float* __restrict__ w1, const float* __restrict__ w2,
        const float* __restrict__ b2, const float* __restrict__ gb,
        float* __restrict__ out, int num_tiles) {
    const int lane = threadIdx.x & 63;
    const int l15  = lane & 15;
    const int g    = lane >> 4;
    const int wid    = (blockIdx.x * blockDim.x + threadIdx.x) >> 6;
    const int nwaves = (gridDim.x * blockDim.x) >> 6;

    // B fragments: B[k][n] = w1[n][k], n = nt*16+l15, k = ks*32 + g*8 + e
    bf16x8 bfrag[2][8];
    #pragma unroll
    for (int nt = 0; nt < 8; ++nt) {
        const float* wr = w1 + (nt * 16 + l15) * (2 * D_LAT);
        #pragma unroll
        for (int ks = 0; ks < 2; ++ks)
            bfrag[ks][nt] = cvt8(wr + ks * 32 + g * 8);
    }
    float w2v[8];
    #pragma unroll
    for (int nt = 0; nt < 8; ++nt) w2v[nt] = w2[nt * 16 + l15];
    const float b2v = b2[0];

    const int tpw = (num_tiles + nwaves - 1) / nwaves;
    const int t0 = wid * tpw;
    const int t1 = (t0 + tpw < num_tiles) ? (t0 + tpw) : num_tiles;

    int   cur_b = -1;
    float gbv[8];

    for (int t = t0; t < t1; ++t) {
        const int rowbase = t * 16;
        // A fragments straight from global: row = rowbase+l15, k = ks*32 + g*8 + e
        const float* arow = embed + (size_t)(rowbase + l15) * D_LAT + g * 8;
        bf16x8 a0 = cvt8(arow);
        bf16x8 a1 = cvt8(arow + 32);

        f32x4 acc[8];
        #pragma unroll
        for (int nt = 0; nt < 8; ++nt) {
            f32x4 z = {0.f, 0.f, 0.f, 0.f};
            z = __builtin_amdgcn_mfma_f32_16x16x32_bf16(a0, bfrag[0][nt], z, 0, 0, 0);
            z = __builtin_amdgcn_mfma_f32_16x16x32_bf16(a1, bfrag[1][nt], z, 0, 0, 0);
            acc[nt] = z;
        }

        const int b_first = rep[rowbase];
        const int b_last  = rep[rowbase + 15];
        float p0 = 0.f, p1 = 0.f, p2 = 0.f, p3 = 0.f;

        if (b_first == b_last) {
            if (b_first != cur_b) {
                #pragma unroll
                for (int nt = 0; nt < 8; ++nt)
                    gbv[nt] = gb[b_first * H_HID + nt * 16 + l15];
                cur_b = b_first;
            }
            #pragma unroll
            for (int nt = 0; nt < 8; ++nt) {
                const float w = w2v[nt];
                p0 += fmaxf(acc[nt][0] + gbv[nt], 0.f) * w;
                p1 += fmaxf(acc[nt][1] + gbv[nt], 0.f) * w;
                p2 += fmaxf(acc[nt][2] + gbv[nt], 0.f) * w;
                p3 += fmaxf(acc[nt][3] + gbv[nt], 0.f) * w;
            }
        } else {
            cur_b = -1;
            const int r0 = rep[rowbase + g * 4 + 0];
            const int r1 = rep[rowbase + g * 4 + 1];
            const int r2 = rep[rowbase + g * 4 + 2];
            const int r3 = rep[rowbase + g * 4 + 3];
            #pragma unroll
            for (int nt = 0; nt < 8; ++nt) {
                const float w = w2v[nt];
                const int c = nt * 16 + l15;
                p0 += fmaxf(acc[nt][0] + gb[r0 * H_HID + c], 0.f) * w;
                p1 += fmaxf(acc[nt][1] + gb[r1 * H_HID + c], 0.f) * w;
                p2 += fmaxf(acc[nt][2] + gb[r2 * H_HID + c], 0.f) * w;
                p3 += fmaxf(acc[nt][3] + gb[r3 * H_HID + c], 0.f) * w;
            }
        }

        // reduce partial dot over the 16 lanes (column groups) sharing row-group g
        #pragma unroll
        for (int m = 1; m <= 8; m <<= 1) {
            p0 += __shfl_xor(p0, m, 64);
            p1 += __shfl_xor(p1, m, 64);
            p2 += __shfl_xor(p2, m, 64);
            p3 += __shfl_xor(p3, m, 64);
        }
        if (l15 < 4) {
            const float pv = (l15 == 0) ? p0 : (l15 == 1) ? p1 : (l15 == 2) ? p2 : p3;
            out[rowbase + g * 4 + l15] = pv + b2v;
        }
    }
}

extern "C" void kernel_launch(void* const* d_in, const int* in_sizes, int n_in,
                              void* d_out, int out_size, void* d_ws, size_t ws_size,
                              hipStream_t stream) {
    const float* embed = (const float*)d_in[0];
    const float* ge    = (const float*)d_in[1];
    const int*   rep   = (const int*)d_in[2];
    const float* w1    = (const float*)d_in[3];
    const float* b1    = (const float*)d_in[4];
    const float* w2    = (const float*)d_in[5];
    const float* b2    = (const float*)d_in[6];
    float* out = (float*)d_out;
    float* gb  = (float*)d_ws;                       // 512*128*4 = 256 KB

    const int N = in_sizes[0] / D_LAT;
    const int B = in_sizes[1] / D_LAT;
    const int num_tiles = N / 16;

    gb_kernel<<<B, H_HID, 0, stream>>>(ge, w1, b1, gb);
    qnet_main<<<2048, 256, 0, stream>>>(embed, rep, w1, w2, b2, gb, out, num_tiles);
}

// Round 2
// 154.092 us; speedup vs baseline: 1.2794x; 1.2794x over previous
//
#include <hip/hip_runtime.h>
#include <hip/hip_bf16.h>

// QNet: out[i] = w2 . relu( concat(embed[i], graph_embed[rep[i]]) @ w1^T + b1 ) + b2
// Split: h_pre = embed @ W1a^T (bf16 MFMA, K=64) + Gb[rep[i]] (precomputed fp32)
// where Gb[b][n] = b1[n] + sum_k graph_embed[b][k] * w1[n][64+k]
//
// MFMA role: A = W1a fragments (resident in VGPRs), B = embed tile.
// C layout (m89-verified): col=lane&15 -> embed row, row=(lane>>4)*4+reg -> hidden idx.
// => epilogue dot over hidden needs only 2 shfl_xor (16,32) and stores are coalesced.

#define D_LAT 64
#define H_HID 128

typedef short bf16x8 __attribute__((ext_vector_type(8)));
typedef float f32x4  __attribute__((ext_vector_type(4)));

static __device__ inline short f2s(float f) {
    __bf16 h = (__bf16)f;               // pairs fuse to v_cvt_pk_bf16_f32
    return __builtin_bit_cast(short, h);
}

static __device__ inline bf16x8 pack8(float4 a, float4 b) {
    bf16x8 r;
    r[0] = f2s(a.x); r[1] = f2s(a.y); r[2] = f2s(a.z); r[3] = f2s(a.w);
    r[4] = f2s(b.x); r[5] = f2s(b.y); r[6] = f2s(b.z); r[7] = f2s(b.w);
    return r;
}

// Gb[b][n] = b1[n] + sum_{k<64} graph_embed[b][k] * w1[n][64+k]
__global__ void gb_kernel(const float* __restrict__ ge, const float* __restrict__ w1,
                          const float* __restrict__ b1, float* __restrict__ gb) {
    __shared__ float s[D_LAT];
    const int b = blockIdx.x, n = threadIdx.x;
    if (threadIdx.x < D_LAT) s[threadIdx.x] = ge[b * D_LAT + threadIdx.x];
    __syncthreads();
    float acc = b1[n];
    const float* wr = w1 + n * (2 * D_LAT) + D_LAT;
    #pragma unroll
    for (int k = 0; k < D_LAT; ++k) acc += s[k] * wr[k];
    gb[b * H_HID + n] = acc;
}

__global__ __launch_bounds__(256) void qnet_main(
        const float* __restrict__ embed, const int* __restrict__ rep,
        const float* __restrict__ w1, const float* __restrict__ w2,
        const float* __restrict__ b2, const float* __restrict__ gb,
        float* __restrict__ out, int num_tiles) {
    const int lane = threadIdx.x & 63;
    const int l15  = lane & 15;
    const int g    = lane >> 4;
    const int wid    = (blockIdx.x * blockDim.x + threadIdx.x) >> 6;
    const int nwaves = (gridDim.x * blockDim.x) >> 6;

    // A fragments (W1a): lane holds w1[nt*16+l15][ks*32 + g*8 + e]
    bf16x8 wfrag[2][8];
    #pragma unroll
    for (int nt = 0; nt < 8; ++nt) {
        const float* wr = w1 + (nt * 16 + l15) * (2 * D_LAT);
        #pragma unroll
        for (int ks = 0; ks < 2; ++ks) {
            float4 lo = *reinterpret_cast<const float4*>(wr + ks * 32 + g * 8);
            float4 hi = *reinterpret_cast<const float4*>(wr + ks * 32 + g * 8 + 4);
            wfrag[ks][nt] = pack8(lo, hi);
        }
    }
    const float b2v = b2[0];

    const int tpw = (num_tiles + nwaves - 1) / nwaves;
    const int t0 = wid * tpw;
    const int t1 = (t0 + tpw < num_tiles) ? (t0 + tpw) : num_tiles;
    if (t0 >= t1) return;

    // Prefetch tile t0: B-fragment rows. lane reads embed row l15 of the tile,
    // k-chunk g*8 (+32 for second K half). Same coalescing as a direct tile read.
    const float* ap = embed + (size_t)(t0 * 16 + l15) * D_LAT + g * 8;
    float4 f0 = *reinterpret_cast<const float4*>(ap);
    float4 f1 = *reinterpret_cast<const float4*>(ap + 4);
    float4 f2v = *reinterpret_cast<const float4*>(ap + 32);
    float4 f3 = *reinterpret_cast<const float4*>(ap + 36);
    int bpf = rep[t0 * 16 + l15];

    for (int t = t0; t < t1; ++t) {
        bf16x8 a0 = pack8(f0, f1);
        bf16x8 a1 = pack8(f2v, f3);
        const int bcur = bpf;

        if (t + 1 < t1) {   // issue next tile's loads; they fly under MFMA+epilogue
            const float* an = embed + (size_t)((t + 1) * 16 + l15) * D_LAT + g * 8;
            f0  = *reinterpret_cast<const float4*>(an);
            f1  = *reinterpret_cast<const float4*>(an + 4);
            f2v = *reinterpret_cast<const float4*>(an + 32);
            f3  = *reinterpret_cast<const float4*>(an + 36);
            bpf = rep[(t + 1) * 16 + l15];
        }

        f32x4 acc[8];
        #pragma unroll
        for (int nt = 0; nt < 8; ++nt) {
            f32x4 z = {0.f, 0.f, 0.f, 0.f};
            z = __builtin_amdgcn_mfma_f32_16x16x32_bf16(wfrag[0][nt], a0, z, 0, 0, 0);
            z = __builtin_amdgcn_mfma_f32_16x16x32_bf16(wfrag[1][nt], a1, z, 0, 0, 0);
            acc[nt] = z;
        }

        // epilogue: out[row=l15] = b2 + sum_hidden w2[h]*relu(acc + gb[rep[row]][h])
        // lane's hidden indices: nt*16 + g*4 + r
        const float* gbrow = gb + (size_t)bcur * H_HID + g * 4;
        const float* w2p   = w2 + g * 4;
        float p = 0.f;
        #pragma unroll
        for (int nt = 0; nt < 8; ++nt) {
            f32x4 gv = *reinterpret_cast<const f32x4*>(gbrow + nt * 16);
            f32x4 wv = *reinterpret_cast<const f32x4*>(w2p + nt * 16);
            #pragma unroll
            for (int r = 0; r < 4; ++r)
                p += fmaxf(acc[nt][r] + gv[r], 0.f) * wv[r];
        }
        p += __shfl_xor(p, 16, 64);
        p += __shfl_xor(p, 32, 64);
        if (g == 0) out[t * 16 + l15] = p + b2v;
    }
}

extern "C" void kernel_launch(void* const* d_in, const int* in_sizes, int n_in,
                              void* d_out, int out_size, void* d_ws, size_t ws_size,
                              hipStream_t stream) {
    const float* embed = (const float*)d_in[0];
    const float* ge    = (const float*)d_in[1];
    const int*   rep   = (const int*)d_in[2];
    const float* w1    = (const float*)d_in[3];
    const float* b1    = (const float*)d_in[4];
    const float* w2    = (const float*)d_in[5];
    const float* b2    = (const float*)d_in[6];
    float* out = (float*)d_out;
    float* gb  = (float*)d_ws;                       // 512*128*4 = 256 KB

    const int N = in_sizes[0] / D_LAT;
    const int B = in_sizes[1] / D_LAT;
    const int num_tiles = N / 16;

    gb_kernel<<<B, H_HID, 0, stream>>>(ge, w1, b1, gb);
    qnet_main<<<2048, 256, 0, stream>>>(embed, rep, w1, w2, b2, gb, out, num_tiles);
}

// Round 3
// 134.590 us; speedup vs baseline: 1.4647x; 1.1449x over previous
//
#include <hip/hip_runtime.h>
#include <hip/hip_bf16.h>

// QNet: out[i] = w2 . relu( concat(embed[i], graph_embed[rep[i]]) @ w1^T + b1 ) + b2
// Split: h_pre = embed @ W1a^T (bf16 MFMA, K=64) + Gb[rep[i]] (precomputed fp32)
// where Gb[b][n] = b1[n] + sum_k graph_embed[b][k] * w1[n][64+k]
//
// MFMA role: A = W1a fragments (resident in VGPRs), B = embed tile.
// C layout: col=lane&15 -> embed row, row=(lane>>4)*4+reg -> hidden idx.
// Persistent grid (512 blocks = 2/CU, all resident), grid-stride over tiles,
// 2-deep software pipeline (two named tile slots, ~8KB in flight per wave).

#define D_LAT 64
#define H_HID 128

typedef short bf16x8 __attribute__((ext_vector_type(8)));
typedef float f32x4  __attribute__((ext_vector_type(4)));

static __device__ inline short f2s(float f) {
    __bf16 h = (__bf16)f;               // pairs fuse to v_cvt_pk_bf16_f32
    return __builtin_bit_cast(short, h);
}

static __device__ inline bf16x8 pack8(float4 a, float4 b) {
    bf16x8 r;
    r[0] = f2s(a.x); r[1] = f2s(a.y); r[2] = f2s(a.z); r[3] = f2s(a.w);
    r[4] = f2s(b.x); r[5] = f2s(b.y); r[6] = f2s(b.z); r[7] = f2s(b.w);
    return r;
}

// Gb[b][n] = b1[n] + sum_{k<64} graph_embed[b][k] * w1[n][64+k]
__global__ void gb_kernel(const float* __restrict__ ge, const float* __restrict__ w1,
                          const float* __restrict__ b1, float* __restrict__ gb) {
    __shared__ float s[D_LAT];
    const int b = blockIdx.x, n = threadIdx.x;
    if (threadIdx.x < D_LAT) s[threadIdx.x] = ge[b * D_LAT + threadIdx.x];
    __syncthreads();
    float acc = b1[n];
    const float* wr = w1 + n * (2 * D_LAT) + D_LAT;
    #pragma unroll
    for (int k = 0; k < D_LAT; ++k) acc += s[k] * wr[k];
    gb[b * H_HID + n] = acc;
}

struct TileRegs { float4 f0, f1, f2, f3; int b; };

static __device__ inline TileRegs load_tile(const float* __restrict__ embed,
                                            const int* __restrict__ rep,
                                            int t, int l15, int g) {
    TileRegs r;
    const float* ap = embed + (size_t)(t * 16 + l15) * D_LAT + g * 8;
    r.f0 = *reinterpret_cast<const float4*>(ap);
    r.f1 = *reinterpret_cast<const float4*>(ap + 4);
    r.f2 = *reinterpret_cast<const float4*>(ap + 32);
    r.f3 = *reinterpret_cast<const float4*>(ap + 36);
    r.b  = rep[t * 16 + l15];
    return r;
}

__global__ __launch_bounds__(256, 2) void qnet_main(
        const float* __restrict__ embed, const int* __restrict__ rep,
        const float* __restrict__ w1, const float* __restrict__ w2,
        const float* __restrict__ b2, const float* __restrict__ gb,
        float* __restrict__ out, int num_tiles) {
    const int lane = threadIdx.x & 63;
    const int l15  = lane & 15;
    const int g    = lane >> 4;
    const int wid    = (blockIdx.x * blockDim.x + threadIdx.x) >> 6;
    const int nw     = (gridDim.x * blockDim.x) >> 6;     // total waves
    const int nw2    = nw * 2;

    // A fragments (W1a): lane holds w1[nt*16+l15][ks*32 + g*8 + e]
    bf16x8 wfrag[2][8];
    #pragma unroll
    for (int nt = 0; nt < 8; ++nt) {
        const float* wr = w1 + (nt * 16 + l15) * (2 * D_LAT);
        #pragma unroll
        for (int ks = 0; ks < 2; ++ks) {
            float4 lo = *reinterpret_cast<const float4*>(wr + ks * 32 + g * 8);
            float4 hi = *reinterpret_cast<const float4*>(wr + ks * 32 + g * 8 + 4);
            wfrag[ks][nt] = pack8(lo, hi);
        }
    }
    // epilogue w2 vector, hoisted: lane's hidden indices nt*16 + g*4 + r
    f32x4 w2v[8];
    #pragma unroll
    for (int nt = 0; nt < 8; ++nt)
        w2v[nt] = *reinterpret_cast<const f32x4*>(w2 + nt * 16 + g * 4);
    const float b2v = b2[0];

    if (wid >= num_tiles) return;

    // 2-deep pipeline: slots A (tile t) and B (tile t+nw)
    TileRegs A = load_tile(embed, rep, wid, l15, g);
    {
        int tB = wid + nw;
        TileRegs B = load_tile(embed, rep, tB < num_tiles ? tB : wid, l15, g);

        for (int t = wid; t < num_tiles; t += nw2) {
            // ---- stage 1: consume A, refill A from t + 2*nw ----
            {
                bf16x8 a0 = pack8(A.f0, A.f1);
                bf16x8 a1 = pack8(A.f2, A.f3);
                const int bcur = A.b;
                int tp = t + nw2;
                A = load_tile(embed, rep, tp < num_tiles ? tp : t, l15, g);

                f32x4 acc[8];
                #pragma unroll
                for (int nt = 0; nt < 8; ++nt) {
                    f32x4 z = {0.f, 0.f, 0.f, 0.f};
                    z = __builtin_amdgcn_mfma_f32_16x16x32_bf16(wfrag[0][nt], a0, z, 0, 0, 0);
                    z = __builtin_amdgcn_mfma_f32_16x16x32_bf16(wfrag[1][nt], a1, z, 0, 0, 0);
                    acc[nt] = z;
                }
                const float* gbrow = gb + (size_t)bcur * H_HID + g * 4;
                float p = 0.f;
                #pragma unroll
                for (int nt = 0; nt < 8; ++nt) {
                    f32x4 gv = *reinterpret_cast<const f32x4*>(gbrow + nt * 16);
                    #pragma unroll
                    for (int r = 0; r < 4; ++r)
                        p += fmaxf(acc[nt][r] + gv[r], 0.f) * w2v[nt][r];
                }
                p += __shfl_xor(p, 16, 64);
                p += __shfl_xor(p, 32, 64);
                if (g == 0) out[t * 16 + l15] = p + b2v;
            }
            // ---- stage 2: consume B, refill B from u + 2*nw ----
            int u = t + nw;
            if (u < num_tiles) {
                bf16x8 a0 = pack8(B.f0, B.f1);
                bf16x8 a1 = pack8(B.f2, B.f3);
                const int bcur = B.b;
                int tp = u + nw2;
                B = load_tile(embed, rep, tp < num_tiles ? tp : u, l15, g);

                f32x4 acc[8];
                #pragma unroll
                for (int nt = 0; nt < 8; ++nt) {
                    f32x4 z = {0.f, 0.f, 0.f, 0.f};
                    z = __builtin_amdgcn_mfma_f32_16x16x32_bf16(wfrag[0][nt], a0, z, 0, 0, 0);
                    z = __builtin_amdgcn_mfma_f32_16x16x32_bf16(wfrag[1][nt], a1, z, 0, 0, 0);
                    acc[nt] = z;
                }
                const float* gbrow = gb + (size_t)bcur * H_HID + g * 4;
                float p = 0.f;
                #pragma unroll
                for (int nt = 0; nt < 8; ++nt) {
                    f32x4 gv = *reinterpret_cast<const f32x4*>(gbrow + nt * 16);
                    #pragma unroll
                    for (int r = 0; r < 4; ++r)
                        p += fmaxf(acc[nt][r] + gv[r], 0.f) * w2v[nt][r];
                }
                p += __shfl_xor(p, 16, 64);
                p += __shfl_xor(p, 32, 64);
                if (g == 0) out[u * 16 + l15] = p + b2v;
            }
        }
    }
}

extern "C" void kernel_launch(void* const* d_in, const int* in_sizes, int n_in,
                              void* d_out, int out_size, void* d_ws, size_t ws_size,
                              hipStream_t stream) {
    const float* embed = (const float*)d_in[0];
    const float* ge    = (const float*)d_in[1];
    const int*   rep   = (const int*)d_in[2];
    const float* w1    = (const float*)d_in[3];
    const float* b1    = (const float*)d_in[4];
    const float* w2    = (const float*)d_in[5];
    const float* b2    = (const float*)d_in[6];
    float* out = (float*)d_out;
    float* gb  = (float*)d_ws;                       // 512*128*4 = 256 KB

    const int N = in_sizes[0] / D_LAT;
    const int B = in_sizes[1] / D_LAT;
    const int num_tiles = N / 16;

    gb_kernel<<<B, H_HID, 0, stream>>>(ge, w1, b1, gb);
    // 512 blocks = 2 blocks/CU on 256 CUs -> fully resident, no scheduling rounds
    qnet_main<<<512, 256, 0, stream>>>(embed, rep, w1, w2, b2, gb, out, num_tiles);
}

// Round 4
// 128.183 us; speedup vs baseline: 1.5379x; 1.0500x over previous
//
#include <hip/hip_runtime.h>
#include <hip/hip_bf16.h>

// QNet: out[i] = w2 . relu( concat(embed[i], graph_embed[rep[i]]) @ w1^T + b1 ) + b2
// Split: h_pre = embed @ W1a^T (bf16 MFMA, K=64) + Gb[rep[i]] (precomputed fp32),
// Gb[b][n] = b1[n] + sum_k graph_embed[b][k] * w1[n][64+k].
//
// Pipeline: per-wave private 4-slot LDS ring staged with global_load_lds
// (fire-and-forget), counted s_waitcnt vmcnt(N) in inline asm, ds_read via
// inline asm ending in lgkmcnt(0) (escapes compiler's conservative drains).
// Contiguous 64-tile chunks per wave -> gb row register-cached (cur_b/gbv),
// so steady-state phases have no compiler-tracked global loads.

#define D_LAT 64
#define H_HID 128
#define RING  4
#define WPB   2
#define BLOCK (WPB * 64)
#define NBLK  1024           // 2048 waves total

typedef short bf16x8 __attribute__((ext_vector_type(8)));
typedef float f32x4  __attribute__((ext_vector_type(4)));
typedef __attribute__((address_space(3))) float lds_f;
typedef __attribute__((address_space(3))) int   lds_i;

static __device__ inline short f2s(float f) {
    __bf16 h = (__bf16)f;
    return __builtin_bit_cast(short, h);
}
static __device__ inline bf16x8 pack8(float4 a, float4 b) {
    bf16x8 r;
    r[0] = f2s(a.x); r[1] = f2s(a.y); r[2] = f2s(a.z); r[3] = f2s(a.w);
    r[4] = f2s(b.x); r[5] = f2s(b.y); r[6] = f2s(b.z); r[7] = f2s(b.w);
    return r;
}
static __device__ inline void gll16(const float* g, float* l) {
    __builtin_amdgcn_global_load_lds((const __attribute__((address_space(1))) void*)g,
                                     (__attribute__((address_space(3))) void*)l, 16, 0, 0);
}
static __device__ inline void gll4(const int* g, int* l) {
    __builtin_amdgcn_global_load_lds((const __attribute__((address_space(1))) void*)g,
                                     (__attribute__((address_space(3))) void*)l, 4, 0, 0);
}

// Gb[b][n] = b1[n] + sum_{k<64} graph_embed[b][k] * w1[n][64+k]
__global__ void gb_kernel(const float* __restrict__ ge, const float* __restrict__ w1,
                          const float* __restrict__ b1, float* __restrict__ gb) {
    __shared__ float s[D_LAT];
    const int b = blockIdx.x, n = threadIdx.x;
    if (threadIdx.x < D_LAT) s[threadIdx.x] = ge[b * D_LAT + threadIdx.x];
    __syncthreads();
    float acc = b1[n];
    const float* wr = w1 + n * (2 * D_LAT) + D_LAT;
    #pragma unroll
    for (int k = 0; k < D_LAT; ++k) acc += s[k] * wr[k];
    gb[b * H_HID + n] = acc;
}

__global__ __launch_bounds__(BLOCK, 2) void qnet_main(
        const float* __restrict__ embed, const int* __restrict__ rep,
        const float* __restrict__ w1, const float* __restrict__ w2,
        const float* __restrict__ b2, const float* __restrict__ gb,
        float* __restrict__ out, int num_tiles) {
    __shared__ float s_emb[WPB * RING * 1024];   // 4KB per slot
    __shared__ int   s_rep[WPB * RING * 64];     // 256B per slot (16 used)

    const int lane = threadIdx.x & 63;
    const int l15  = lane & 15;
    const int g    = lane >> 4;
    const int w    = threadIdx.x >> 6;
    const int wid  = blockIdx.x * WPB + w;
    const int nw   = gridDim.x * WPB;

    // A fragments (W1a): lane holds w1[nt*16+l15][ks*32 + g*8 + e]
    bf16x8 wfrag[2][8];
    #pragma unroll
    for (int nt = 0; nt < 8; ++nt) {
        const float* wr = w1 + (nt * 16 + l15) * (2 * D_LAT);
        #pragma unroll
        for (int ks = 0; ks < 2; ++ks) {
            float4 lo = *reinterpret_cast<const float4*>(wr + ks * 32 + g * 8);
            float4 hi = *reinterpret_cast<const float4*>(wr + ks * 32 + g * 8 + 4);
            wfrag[ks][nt] = pack8(lo, hi);
        }
    }
    f32x4 w2v[8];
    #pragma unroll
    for (int nt = 0; nt < 8; ++nt)
        w2v[nt] = *reinterpret_cast<const f32x4*>(w2 + nt * 16 + g * 4);
    const float b2v = b2[0];

    float* semb = s_emb + w * (RING * 1024);
    int*   srep = s_rep + w * (RING * 64);
    const unsigned emb_base = (unsigned)(size_t)(lds_f*)semb;
    const unsigned rep_base = (unsigned)(size_t)(lds_i*)srep;

    const int tpw = num_tiles / nw;      // 64
    const int t0  = wid * tpw;
    const int t1  = t0 + tpw;

    int   cur_b = -1;
    f32x4 gbv[8];
    #pragma unroll
    for (int nt = 0; nt < 8; ++nt) gbv[nt] = f32x4{0.f, 0.f, 0.f, 0.f};

#define STAGE(TT, SLOT) do {                                                  \
    const float* gsrc_ = embed + (size_t)(TT) * 1024 + lane * 4;              \
    float* ldst_ = semb + (SLOT) * 1024;                                      \
    gll16(gsrc_,       ldst_);                                                \
    gll16(gsrc_ + 256, ldst_ + 256);                                          \
    gll16(gsrc_ + 512, ldst_ + 512);                                          \
    gll16(gsrc_ + 768, ldst_ + 768);                                          \
    gll4(rep + (size_t)(TT) * 16 + l15, srep + (SLOT) * 64);                  \
} while (0)

#define PHASE(CS, SS, TT, WAITN) do {                                         \
    asm volatile("s_waitcnt vmcnt(" #WAITN ")" ::: "memory");                 \
    f32x4 x0, x1, x2, x3; int brow;                                           \
    {                                                                         \
        unsigned ae_ = emb_base + (CS) * 4096 + l15 * 256 + g * 32;           \
        unsigned ar_ = rep_base + (CS) * 256 + l15 * 4;                       \
        asm volatile(                                                         \
            "ds_read_b128 %0, %5\n\t"                                         \
            "ds_read_b128 %1, %5 offset:16\n\t"                               \
            "ds_read_b128 %2, %5 offset:128\n\t"                              \
            "ds_read_b128 %3, %5 offset:144\n\t"                              \
            "ds_read_b32  %4, %6\n\t"                                         \
            "s_waitcnt lgkmcnt(0)"                                            \
            : "=&v"(x0), "=&v"(x1), "=&v"(x2), "=&v"(x3), "=&v"(brow)         \
            : "v"(ae_), "v"(ar_)                                              \
            : "memory");                                                      \
    }                                                                         \
    if ((TT) + 3 < t1) STAGE((TT) + 3, SS);                                   \
    const int rb0  = __shfl(brow, 0, 64);                                     \
    const int rb15 = __shfl(brow, 15, 64);                                    \
    bf16x8 a0 = pack8(*(float4*)&x0, *(float4*)&x1);                          \
    bf16x8 a1 = pack8(*(float4*)&x2, *(float4*)&x3);                          \
    f32x4 acc[8];                                                             \
    _Pragma("unroll")                                                         \
    for (int nt = 0; nt < 8; ++nt) {                                          \
        f32x4 z = {0.f, 0.f, 0.f, 0.f};                                       \
        z = __builtin_amdgcn_mfma_f32_16x16x32_bf16(wfrag[0][nt], a0, z, 0, 0, 0); \
        z = __builtin_amdgcn_mfma_f32_16x16x32_bf16(wfrag[1][nt], a1, z, 0, 0, 0); \
        acc[nt] = z;                                                          \
    }                                                                         \
    float p = 0.f;                                                            \
    if (rb0 == rb15) {                                                        \
        if (rb0 != cur_b) {                                                   \
            _Pragma("unroll")                                                 \
            for (int nt = 0; nt < 8; ++nt)                                    \
                gbv[nt] = *(const f32x4*)(gb + (size_t)rb0 * H_HID + nt * 16 + g * 4); \
            cur_b = rb0;                                                      \
        }                                                                     \
        _Pragma("unroll")                                                     \
        for (int nt = 0; nt < 8; ++nt) {                                      \
            _Pragma("unroll")                                                 \
            for (int r = 0; r < 4; ++r)                                       \
                p += fmaxf(acc[nt][r] + gbv[nt][r], 0.f) * w2v[nt][r];        \
        }                                                                     \
    } else {                                                                  \
        const float* gbrow_ = gb + (size_t)brow * H_HID + g * 4;              \
        _Pragma("unroll")                                                     \
        for (int nt = 0; nt < 8; ++nt) {                                      \
            f32x4 gv = *(const f32x4*)(gbrow_ + nt * 16);                     \
            _Pragma("unroll")                                                 \
            for (int r = 0; r < 4; ++r)                                       \
                p += fmaxf(acc[nt][r] + gv[r], 0.f) * w2v[nt][r];             \
        }                                                                     \
    }                                                                         \
    p += __shfl_xor(p, 16, 64);                                               \
    p += __shfl_xor(p, 32, 64);                                               \
    if (g == 0) out[(TT) * 16 + l15] = p + b2v;                               \
} while (0)

    // prologue: 3 tiles in flight
    STAGE(t0 + 0, 0);
    STAGE(t0 + 1, 1);
    STAGE(t0 + 2, 2);

    // first iteration peeled (exact wait counts while pipeline fills)
    PHASE(0, 3, t0 + 0, 10);
    PHASE(1, 0, t0 + 1, 11);
    PHASE(2, 1, t0 + 2, 12);
    PHASE(3, 2, t0 + 3, 13);
    // steady state: 2 staged tiles + 3 stores in flight -> vmcnt(13)
    for (int i = 4; i + 4 < tpw; i += 4) {
        PHASE(0, 3, t0 + i + 0, 13);
        PHASE(1, 0, t0 + i + 1, 13);
        PHASE(2, 1, t0 + i + 2, 13);
        PHASE(3, 2, t0 + i + 3, 13);
    }
    // last iteration peeled (staging stops -> tighter waits)
    PHASE(0, 3, t1 - 4, 13);
    PHASE(1, 0, t1 - 3, 13);
    PHASE(2, 1, t1 - 2, 8);
    PHASE(3, 2, t1 - 1, 3);

#undef PHASE
#undef STAGE
}

extern "C" void kernel_launch(void* const* d_in, const int* in_sizes, int n_in,
                              void* d_out, int out_size, void* d_ws, size_t ws_size,
                              hipStream_t stream) {
    const float* embed = (const float*)d_in[0];
    const float* ge    = (const float*)d_in[1];
    const int*   rep   = (const int*)d_in[2];
    const float* w1    = (const float*)d_in[3];
    const float* b1    = (const float*)d_in[4];
    const float* w2    = (const float*)d_in[5];
    const float* b2    = (const float*)d_in[6];
    float* out = (float*)d_out;
    float* gb  = (float*)d_ws;                       // 512*128*4 = 256 KB

    const int N = in_sizes[0] / D_LAT;
    const int B = in_sizes[1] / D_LAT;
    const int num_tiles = N / 16;

    gb_kernel<<<B, H_HID, 0, stream>>>(ge, w1, b1, gb);
    // 1024 blocks x 128 thr = 2048 waves; 4 blocks/CU (34KB LDS each), 64 tiles/wave
    qnet_main<<<NBLK, BLOCK, 0, stream>>>(embed, rep, w1, w2, b2, gb, out, num_tiles);
}

// Round 5
// 125.311 us; speedup vs baseline: 1.5732x; 1.0229x over previous
//
#include <hip/hip_runtime.h>
#include <hip/hip_bf16.h>

// QNet: out[i] = w2 . relu( concat(embed[i], graph_embed[rep[i]]) @ w1^T + b1 ) + b2
// Split: pre = embed @ W1a^T (bf16 MFMA, K=64) + Gb[rep[i]] (fp32, folded into MFMA C-init),
// Gb[b][n] = b1[n] + sum_k graph_embed[b][k] * w1[n][64+k].
//
// Structure: 2048 blocks x 2 waves. Waves split the hidden dim (64 each):
// wfrag/w2v/gbv/acc halve -> VGPR <= 128 -> 16 waves/CU (2x memory streams).
// Shared 4-slot LDS ring staged via global_load_lds with k-major pre-swizzled
// GLOBAL source (LDS dest stays linear) so ds_read_b128 is 2-way-conflict-free.
// Raw s_barrier + per-wave counted vmcnt (never __syncthreads -> vmcnt(0) drain).
// Partial dots combined via double-buffered LDS exchange, pipelined one phase.

#define D_LAT 64
#define H_HID 128
#define RING  4
#define TPB   64     // tiles per block

typedef short bf16x8 __attribute__((ext_vector_type(8)));
typedef float f32x4  __attribute__((ext_vector_type(4)));
typedef __attribute__((address_space(3))) float lds_f;

#define MFMA16 __builtin_amdgcn_mfma_f32_16x16x32_bf16

static __device__ inline short f2s(float f) {
    __bf16 h = (__bf16)f;
    return __builtin_bit_cast(short, h);
}
static __device__ inline bf16x8 pack8(f32x4 a, f32x4 b) {
    bf16x8 r;
    r[0] = f2s(a[0]); r[1] = f2s(a[1]); r[2] = f2s(a[2]); r[3] = f2s(a[3]);
    r[4] = f2s(b[0]); r[5] = f2s(b[1]); r[6] = f2s(b[2]); r[7] = f2s(b[3]);
    return r;
}
static __device__ inline void gll16(const float* g, float* l) {
    __builtin_amdgcn_global_load_lds((const __attribute__((address_space(1))) void*)g,
                                     (__attribute__((address_space(3))) void*)l, 16, 0, 0);
}
static __device__ inline void gll4(const int* g, int* l) {
    __builtin_amdgcn_global_load_lds((const __attribute__((address_space(1))) void*)g,
                                     (__attribute__((address_space(3))) void*)l, 4, 0, 0);
}

// Gb[b][n] = b1[n] + sum_{k<64} graph_embed[b][k] * w1[n][64+k]
__global__ void gb_kernel(const float* __restrict__ ge, const float* __restrict__ w1,
                          const float* __restrict__ b1, float* __restrict__ gb) {
    __shared__ float s[D_LAT];
    const int b = blockIdx.x, n = threadIdx.x;
    if (threadIdx.x < D_LAT) s[threadIdx.x] = ge[b * D_LAT + threadIdx.x];
    __syncthreads();
    float acc = b1[n];
    const float* wr = w1 + n * (2 * D_LAT) + D_LAT;
    #pragma unroll
    for (int k = 0; k < D_LAT; ++k) acc += s[k] * wr[k];
    gb[b * H_HID + n] = acc;
}

__global__ __launch_bounds__(128, 4) void qnet_main(
        const float* __restrict__ embed, const int* __restrict__ rep,
        const float* __restrict__ w1, const float* __restrict__ w2,
        const float* __restrict__ b2, const float* __restrict__ gb,
        float* __restrict__ out) {
    __shared__ float s_emb[RING * 1024];   // 4KB per slot, k-major 16B-unit layout
    __shared__ int   s_rep[RING * 64];
    __shared__ float s_exch[2 * 16];

    const int lane = threadIdx.x & 63;
    const int l15  = lane & 15;
    const int g    = lane >> 4;
    const int w    = threadIdx.x >> 6;        // wave role: 0 / 1 (hidden half)
    const int t0   = blockIdx.x * TPB;

    // A fragments: this wave's hidden half. lane holds w1[w*64+nt*16+l15][ks*32+g*8+e]
    bf16x8 wfrag[2][4];
    #pragma unroll
    for (int nt = 0; nt < 4; ++nt) {
        const float* wr = w1 + (w * 64 + nt * 16 + l15) * (2 * D_LAT);
        #pragma unroll
        for (int ks = 0; ks < 2; ++ks) {
            f32x4 lo = *reinterpret_cast<const f32x4*>(wr + ks * 32 + g * 8);
            f32x4 hi = *reinterpret_cast<const f32x4*>(wr + ks * 32 + g * 8 + 4);
            wfrag[ks][nt] = pack8(lo, hi);
        }
    }
    f32x4 w2v[4];
    #pragma unroll
    for (int nt = 0; nt < 4; ++nt)
        w2v[nt] = *reinterpret_cast<const f32x4*>(w2 + w * 64 + nt * 16 + g * 4);
    const float b2v = b2[0];

    const unsigned emb_base  = (unsigned)(size_t)(lds_f*)s_emb;
    const unsigned rep_base  = (unsigned)(size_t)(lds_f*)(float*)(void*)s_rep;
    const unsigned exch_base = (unsigned)(size_t)(lds_f*)s_exch;

    int   cur_b = -2;
    f32x4 gbv[4];
    #pragma unroll
    for (int nt = 0; nt < 4; ++nt) gbv[nt] = f32x4{0.f, 0.f, 0.f, 0.f};
    float p_prev = 0.f;

    // k-major pre-swizzled global source: LDS 16B-unit U = j*64+lane holds
    // global unit (row=lane&15, u=j*4+(lane>>4)); src floats = (lane&15)*64 + j*16 + (lane>>4)*4.
#define STAGE_W0(TT, SLOT) do {                                               \
    const float* s0_ = embed + (size_t)(TT) * 1024 + l15 * 64 + g * 4;        \
    float* d_ = s_emb + (SLOT) * 1024;                                        \
    gll16(s0_,      d_);                                                      \
    gll16(s0_ + 16, d_ + 256);                                                \
    gll4(rep + (size_t)(TT) * 16 + l15, s_rep + (SLOT) * 64);                 \
} while (0)
#define STAGE_W1(TT, SLOT) do {                                               \
    const float* s0_ = embed + (size_t)(TT) * 1024 + l15 * 64 + g * 4;        \
    float* d_ = s_emb + (SLOT) * 1024;                                        \
    gll16(s0_ + 32, d_ + 512);                                                \
    gll16(s0_ + 48, d_ + 768);                                                \
} while (0)

    // shared compute tail: refill gbv on graph change, MFMA (C-init = gbv), dot half
#define COMPUTE(P)                                                            \
    int rb0 = __shfl(brow, 0, 64), rb15 = __shfl(brow, 15, 64);               \
    bool uni = (rb0 == rb15);                                                 \
    if (!(uni && rb0 == cur_b)) {                                             \
        const float* gp = gb + (size_t)brow * H_HID + w * 64 + g * 4;         \
        gbv[0] = *(const f32x4*)(gp);                                         \
        gbv[1] = *(const f32x4*)(gp + 16);                                    \
        gbv[2] = *(const f32x4*)(gp + 32);                                    \
        gbv[3] = *(const f32x4*)(gp + 48);                                    \
        cur_b = uni ? rb0 : -1;                                               \
    }                                                                         \
    bf16x8 a0 = pack8(x0, x1), a1 = pack8(x2, x3);                            \
    float P = 0.f;                                                            \
    _Pragma("unroll")                                                         \
    for (int nt = 0; nt < 4; ++nt) {                                          \
        f32x4 z = gbv[nt];                                                    \
        z = MFMA16(wfrag[0][nt], a0, z, 0, 0, 0);                             \
        z = MFMA16(wfrag[1][nt], a1, z, 0, 0, 0);                             \
        _Pragma("unroll")                                                     \
        for (int r = 0; r < 4; ++r) P += fmaxf(z[r], 0.f) * w2v[nt][r];       \
    }                                                                         \
    P += __shfl_xor(P, 16, 64);                                               \
    P += __shfl_xor(P, 32, 64);

#define PH0(CS, TT, I, WN, DOSTAGE, DOSTORE) do {                             \
    asm volatile("s_waitcnt vmcnt(" #WN ")" ::: "memory");                    \
    __builtin_amdgcn_s_barrier();                                             \
    f32x4 x0, x1, x2, x3; int brow; float xv;                                 \
    {                                                                         \
        unsigned ae = emb_base + (unsigned)(CS) * 4096u + g * 512u + l15 * 16u; \
        unsigned ar = rep_base + (unsigned)(CS) * 256u + l15 * 4u;            \
        unsigned ax = exch_base + (unsigned)(((I) - 1) & 1) * 64u + l15 * 4u; \
        asm volatile(                                                         \
            "ds_read_b128 %0, %6\n\t"                                         \
            "ds_read_b128 %1, %6 offset:256\n\t"                              \
            "ds_read_b128 %2, %6 offset:2048\n\t"                             \
            "ds_read_b128 %3, %6 offset:2304\n\t"                             \
            "ds_read_b32  %4, %7\n\t"                                         \
            "ds_read_b32  %5, %8\n\t"                                         \
            "s_waitcnt lgkmcnt(0)"                                            \
            : "=&v"(x0), "=&v"(x1), "=&v"(x2), "=&v"(x3), "=&v"(brow), "=&v"(xv) \
            : "v"(ae), "v"(ar), "v"(ax) : "memory");                          \
    }                                                                         \
    if (DOSTORE) { if (g == 0) out[((TT) - 1) * 16 + l15] = p_prev + xv + b2v; } \
    if (DOSTAGE) STAGE_W0((TT) + 3, ((CS) + 3) & 3);                          \
    COMPUTE(p)                                                                \
    p_prev = p;                                                               \
} while (0)

#define PH1(CS, TT, I, WN, DOSTAGE) do {                                      \
    asm volatile("s_waitcnt vmcnt(" #WN ") lgkmcnt(0)" ::: "memory");         \
    __builtin_amdgcn_s_barrier();                                             \
    f32x4 x0, x1, x2, x3; int brow;                                           \
    {                                                                         \
        unsigned ae = emb_base + (unsigned)(CS) * 4096u + g * 512u + l15 * 16u; \
        unsigned ar = rep_base + (unsigned)(CS) * 256u + l15 * 4u;            \
        asm volatile(                                                         \
            "ds_read_b128 %0, %5\n\t"                                         \
            "ds_read_b128 %1, %5 offset:256\n\t"                              \
            "ds_read_b128 %2, %5 offset:2048\n\t"                             \
            "ds_read_b128 %3, %5 offset:2304\n\t"                             \
            "ds_read_b32  %4, %6\n\t"                                         \
            "s_waitcnt lgkmcnt(0)"                                            \
            : "=&v"(x0), "=&v"(x1), "=&v"(x2), "=&v"(x3), "=&v"(brow)         \
            : "v"(ae), "v"(ar) : "memory");                                   \
    }                                                                         \
    if (DOSTAGE) STAGE_W1((TT) + 3, ((CS) + 3) & 3);                          \
    COMPUTE(p)                                                                \
    {                                                                         \
        unsigned ax = exch_base + (unsigned)((I) & 1) * 64u + l15 * 4u;       \
        if (g == 0)                                                           \
            asm volatile("ds_write_b32 %0, %1" :: "v"(ax), "v"(p) : "memory"); \
    }                                                                         \
} while (0)

    if (w == 0) {
        STAGE_W0(t0 + 0, 0);
        STAGE_W0(t0 + 1, 1);
        STAGE_W0(t0 + 2, 2);
        // waits: drain own stage (3 ops/phase) with 1 store/phase interleaved
        PH0(0, t0 + 0, 0, 6, true, false);
        PH0(1, t0 + 1, 1, 6, true, true);
        PH0(2, t0 + 2, 2, 7, true, true);
        for (int i = 3; i <= 60; ++i)
            PH0((i & 3), t0 + i, i, 8, true, true);
        PH0(1, t0 + 61, 61, 8, false, true);
        PH0(2, t0 + 62, 62, 5, false, true);
        PH0(3, t0 + 63, 63, 2, false, true);
        // final combine for tile t0+63
        __builtin_amdgcn_s_barrier();
        float xv;
        unsigned ax = exch_base + (unsigned)(63 & 1) * 64u + l15 * 4u;
        asm volatile("ds_read_b32 %0, %1\n\ts_waitcnt lgkmcnt(0)"
                     : "=v"(xv) : "v"(ax) : "memory");
        if (g == 0) out[(t0 + 63) * 16 + l15] = p_prev + xv + b2v;
    } else {
        STAGE_W1(t0 + 0, 0);
        STAGE_W1(t0 + 1, 1);
        STAGE_W1(t0 + 2, 2);
        PH1(0, t0 + 0, 0, 4, true);
        PH1(1, t0 + 1, 1, 4, true);
        PH1(2, t0 + 2, 2, 4, true);
        for (int i = 3; i <= 60; ++i)
            PH1((i & 3), t0 + i, i, 4, true);
        PH1(1, t0 + 61, 61, 4, false);
        PH1(2, t0 + 62, 62, 2, false);
        PH1(3, t0 + 63, 63, 0, false);
        asm volatile("s_waitcnt lgkmcnt(0)" ::: "memory");
        __builtin_amdgcn_s_barrier();
    }

#undef PH0
#undef PH1
#undef COMPUTE
#undef STAGE_W0
#undef STAGE_W1
}

extern "C" void kernel_launch(void* const* d_in, const int* in_sizes, int n_in,
                              void* d_out, int out_size, void* d_ws, size_t ws_size,
                              hipStream_t stream) {
    const float* embed = (const float*)d_in[0];
    const float* ge    = (const float*)d_in[1];
    const int*   rep   = (const int*)d_in[2];
    const float* w1    = (const float*)d_in[3];
    const float* b1    = (const float*)d_in[4];
    const float* w2    = (const float*)d_in[5];
    const float* b2    = (const float*)d_in[6];
    float* out = (float*)d_out;
    float* gb  = (float*)d_ws;                       // 512*128*4 = 256 KB

    const int N = in_sizes[0] / D_LAT;
    const int B = in_sizes[1] / D_LAT;
    const int num_tiles = N / 16;

    gb_kernel<<<B, H_HID, 0, stream>>>(ge, w1, b1, gb);
    // 2048 blocks x 128 thr (2 waves, hidden-split); 17.2KB LDS -> 8 blocks/CU target
    qnet_main<<<num_tiles / TPB, 128, 0, stream>>>(embed, rep, w1, w2, b2, gb, out);
}